// Round 1
// baseline (378.728 us; speedup 1.0000x reference)
//
#include <hip/hip_runtime.h>

typedef __bf16 bf16x8 __attribute__((ext_vector_type(8)));
typedef float  f32x4  __attribute__((ext_vector_type(4)));
typedef unsigned int u32x4 __attribute__((ext_vector_type(4)));
typedef unsigned int u32x2 __attribute__((ext_vector_type(2)));
typedef unsigned int u32;
typedef unsigned short u16;

#define DEVI static __device__ __forceinline__

// Bn=2048, L=64, C=256, NH=8, HD=32
static constexpr float KSCALE = 0.17677669529663687f;  // 32^-0.5

DEVI u32 pk2(float a, float b){
  u16 ha = __builtin_bit_cast(u16, (__bf16)a);
  u16 hb = __builtin_bit_cast(u16, (__bf16)b);
  return (u32)ha | ((u32)hb << 16);
}
DEVI float bfl(u32 bits16){            // low 16 bits hold a bf16
  union { u32 i; float f; } v; v.i = bits16 << 16; return v.f;
}
DEVI bf16x8 ld16(const void* p){ return __builtin_bit_cast(bf16x8, *(const u32x4*)p); }
DEVI f32x4 mfma16(bf16x8 a, bf16x8 b, f32x4 c){
  return __builtin_amdgcn_mfma_f32_16x16x32_bf16(a, b, c, 0, 0, 0);
}

template<bool BW>
DEVI bf16x8 loadw(const u16* wbp, const float* wfp){
  if constexpr (BW){
    return ld16(wbp);
  } else {
    f32x4 a = *(const f32x4*)wfp;
    f32x4 b = *(const f32x4*)(wfp + 4);
    u32x4 pc; pc[0]=pk2(a[0],a[1]); pc[1]=pk2(a[2],a[3]); pc[2]=pk2(b[0],b[1]); pc[3]=pk2(b[2],b[3]);
    return __builtin_bit_cast(bf16x8, pc);
  }
}

// convert the 4 weight matrices (each 256x256 f32, row-major [j][c]) to bf16 in ws
__global__ void prep_w(const float* __restrict__ qw, const float* __restrict__ kw,
                       const float* __restrict__ vw, const float* __restrict__ pw,
                       u16* __restrict__ dst){
  int i = (blockIdx.x*256 + threadIdx.x) * 4;
  const float* srcs[4] = {qw, kw, vw, pw};
  #pragma unroll
  for (int m = 0; m < 4; ++m){
    f32x4 v = *(const f32x4*)(srcs[m] + i);
    u32x2 o; o[0] = pk2(v[0], v[1]); o[1] = pk2(v[2], v[3]);
    *(u32x2*)(dst + m*65536 + i) = o;
  }
}

// One block per batch item. 256 threads = 4 waves; wave w owns heads {2w,2w+1}
// (channel cols [64w,64w+64)).  LDS 80KB: r1[64][256]bf16 (pitch 512B, XOR-swizzled)
// + per-wave {Qh[64][32], Kh[64][32] (pitch 64B), VT[32][64] (pitch 128B),
//   P[64][64] (pitch 128B) aliased over Qh+Kh}.
template<bool BW>
__global__ __launch_bounds__(256, 2)
void fused_ca(const float* __restrict__ x, const float* __restrict__ y,
              const u16* __restrict__ wb,
              const float* __restrict__ qwf, const float* __restrict__ kwf,
              const float* __restrict__ vwf, const float* __restrict__ pwf,
              const float* __restrict__ qb, const float* __restrict__ kb,
              const float* __restrict__ vb, const float* __restrict__ pb,
              float* __restrict__ out)
{
  extern __shared__ char smem[];
  const int b  = blockIdx.x;
  const int t  = threadIdx.x;
  const int w  = t >> 6;
  const int l  = t & 63;
  const int lo = l & 15;
  const int g  = l >> 4;
  const u32 swr = (u32)(lo & 7) << 4;   // row-XOR swizzle, 128B/512B pitch buffers
  const u32 sw4 = (u32)(lo & 3) << 4;   // row-XOR swizzle, 64B pitch buffers

  char* r1 = smem;                      // Y then (y+y1), bf16
  char* wbp = smem + 32768 + w*12288;
  char* Qh = wbp;                       // [i][d] head-slice, pitch 64B
  char* Kh = wbp + 4096;                // [k][d] head-slice, pitch 64B
  char* VT = wbp + 8192;                // [d][k] (V^T), pitch 128B
  char* Ph = wbp;                       // [q][k], pitch 128B, aliases Qh+Kh

  const float* yb = y + (size_t)b * 16384;
  const float* xb = x + (size_t)b * 16384;

  // ---- stage Y -> r1 (bf16, swizzled) ----
  #pragma unroll
  for (int j = 0; j < 16; ++j){
    int idx = t + 256*j;
    int row = idx >> 6;
    int c0  = (idx & 63) * 4;
    f32x4 v = *(const f32x4*)(yb + row*256 + c0);
    u32x2 o; o[0] = pk2(v[0], v[1]); o[1] = pk2(v[2], v[3]);
    *(u32x2*)(r1 + row*512 + ((u32)(c0*2) ^ ((u32)(row&7) << 4))) = o;
  }
  __syncthreads();

  f32x4 y1a[2][2][4] = {};   // [head][d-frag][q-frag] : Y1^T[d][q] accumulators

  #pragma unroll
  for (int hl = 0; hl < 2; ++hl){
    const int cb = w*64 + hl*32;   // global channel base of this head

    // ---- Q-GEMM (transposed: D[j][i] = sum_c qw[j][c] * Y[i][c]) ----
    f32x4 aq[2][4] = {};
    #pragma unroll
    for (int kk = 0; kk < 8; ++kk){
      bf16x8 A[2], Bf[4];
      #pragma unroll
      for (int m = 0; m < 2; ++m){
        int off = (cb + 16*m + lo)*256 + kk*32 + 8*g;
        A[m] = loadw<BW>(wb + off, qwf + off);
      }
      #pragma unroll
      for (int n = 0; n < 4; ++n)
        Bf[n] = ld16(r1 + (16*n+lo)*512 + ((u32)(kk*64 + 16*g) ^ swr));
      #pragma unroll
      for (int m = 0; m < 2; ++m)
        #pragma unroll
        for (int n = 0; n < 4; ++n)
          aq[m][n] = mfma16(A[m], Bf[n], aq[m][n]);
    }
    #pragma unroll
    for (int m = 0; m < 2; ++m){
      f32x4 bias = *(const f32x4*)(qb + cb + 16*m + 4*g);
      #pragma unroll
      for (int n = 0; n < 4; ++n){
        float v0 = (aq[m][n][0] + bias[0]) * KSCALE;
        float v1 = (aq[m][n][1] + bias[1]) * KSCALE;
        float v2 = (aq[m][n][2] + bias[2]) * KSCALE;
        float v3 = (aq[m][n][3] + bias[3]) * KSCALE;
        u32x2 o; o[0] = pk2(v0, v1); o[1] = pk2(v2, v3);
        *(u32x2*)(Qh + (16*n+lo)*64 + ((u32)(32*m + 8*g) ^ sw4)) = o;
      }
    }

    // ---- fused K-GEMM (transposed) + V-GEMM (normal), sharing X fragments ----
    f32x4 ak[2][4] = {};   // [j-frag][i-frag]
    f32x4 av[4][2] = {};   // [i-frag][j-frag]
    #pragma unroll
    for (int kk = 0; kk < 8; ++kk){
      bf16x8 WA[2], WB2[2], XF[4];
      #pragma unroll
      for (int m = 0; m < 2; ++m){
        int off = (cb + 16*m + lo)*256 + kk*32 + 8*g;
        WA[m] = loadw<BW>(wb + 65536 + off, kwf + off);
      }
      #pragma unroll
      for (int n = 0; n < 2; ++n){
        int off = (cb + 16*n + lo)*256 + kk*32 + 8*g;
        WB2[n] = loadw<BW>(wb + 131072 + off, vwf + off);
      }
      #pragma unroll
      for (int f = 0; f < 4; ++f){
        const float* px = xb + (16*f + lo)*256 + kk*32 + 8*g;
        f32x4 u0 = *(const f32x4*)px;
        f32x4 u1 = *(const f32x4*)(px + 4);
        u32x4 pc; pc[0]=pk2(u0[0],u0[1]); pc[1]=pk2(u0[2],u0[3]);
                  pc[2]=pk2(u1[0],u1[1]); pc[3]=pk2(u1[2],u1[3]);
        XF[f] = __builtin_bit_cast(bf16x8, pc);
      }
      #pragma unroll
      for (int f = 0; f < 4; ++f){
        #pragma unroll
        for (int m = 0; m < 2; ++m)
          ak[m][f] = mfma16(WA[m], XF[f], ak[m][f]);
        #pragma unroll
        for (int n = 0; n < 2; ++n)
          av[f][n] = mfma16(XF[f], WB2[n], av[f][n]);
      }
    }
    #pragma unroll
    for (int m = 0; m < 2; ++m){
      f32x4 bias = *(const f32x4*)(kb + cb + 16*m + 4*g);
      #pragma unroll
      for (int f = 0; f < 4; ++f){
        u32x2 o; o[0] = pk2(ak[m][f][0]+bias[0], ak[m][f][1]+bias[1]);
                 o[1] = pk2(ak[m][f][2]+bias[2], ak[m][f][3]+bias[3]);
        *(u32x2*)(Kh + (16*f+lo)*64 + ((u32)(32*m + 8*g) ^ sw4)) = o;
      }
    }
    #pragma unroll
    for (int n = 0; n < 2; ++n){
      float bias = vb[cb + 16*n + lo];
      #pragma unroll
      for (int f = 0; f < 4; ++f){
        u32x2 o; o[0] = pk2(av[f][n][0]+bias, av[f][n][1]+bias);
                 o[1] = pk2(av[f][n][2]+bias, av[f][n][3]+bias);
        *(u32x2*)(VT + (16*n+lo)*128 + ((u32)(32*f + 8*g) ^ swr)) = o;
      }
    }

    // ---- S^T = K @ Q^T  (one K=32 MFMA per 16x16 fragment) ----
    bf16x8 Kf[4], Qf[4];
    #pragma unroll
    for (int m = 0; m < 4; ++m)
      Kf[m] = ld16(Kh + (16*m+lo)*64 + ((u32)(16*g) ^ sw4));
    #pragma unroll
    for (int n = 0; n < 4; ++n)
      Qf[n] = ld16(Qh + (16*n+lo)*64 + ((u32)(16*g) ^ sw4));
    f32x4 s[4][4];
    const f32x4 zero = {};
    #pragma unroll
    for (int m = 0; m < 4; ++m)
      #pragma unroll
      for (int n = 0; n < 4; ++n)
        s[m][n] = mfma16(Kf[m], Qf[n], zero);

    // ---- softmax_plus_one over k (rows of S^T): 16 local + 2 shfl ----
    #pragma unroll
    for (int n = 0; n < 4; ++n){
      float mx = s[0][n][0];
      #pragma unroll
      for (int m = 0; m < 4; ++m)
        #pragma unroll
        for (int r = 0; r < 4; ++r)
          mx = fmaxf(mx, s[m][n][r]);
      mx = fmaxf(mx, __shfl_xor(mx, 16));
      mx = fmaxf(mx, __shfl_xor(mx, 32));
      float sum = 0.f;
      #pragma unroll
      for (int m = 0; m < 4; ++m)
        #pragma unroll
        for (int r = 0; r < 4; ++r){
          float e = __expf(s[m][n][r] - mx);
          s[m][n][r] = e; sum += e;
        }
      sum += __shfl_xor(sum, 16);
      sum += __shfl_xor(sum, 32);
      float rin = 1.0f / (sum + 1.0f);
      #pragma unroll
      for (int m = 0; m < 4; ++m)
        #pragma unroll
        for (int r = 0; r < 4; ++r)
          s[m][n][r] *= rin;
    }

    // ---- write P[q][k] bf16 (Qh/Kh dead now; Ph aliases them) ----
    #pragma unroll
    for (int m = 0; m < 4; ++m)
      #pragma unroll
      for (int n = 0; n < 4; ++n){
        u32x2 o; o[0] = pk2(s[m][n][0], s[m][n][1]);
                 o[1] = pk2(s[m][n][2], s[m][n][3]);
        *(u32x2*)(Ph + (16*n+lo)*128 + ((u32)(32*m + 8*g) ^ swr)) = o;
      }

    // ---- PV: Y1^T = V^T @ P^T ----
    #pragma unroll
    for (int kk2 = 0; kk2 < 2; ++kk2){
      bf16x8 Vf[2], Pf[4];
      #pragma unroll
      for (int md = 0; md < 2; ++md)
        Vf[md] = ld16(VT + (16*md+lo)*128 + ((u32)(16*g + 64*kk2) ^ swr));
      #pragma unroll
      for (int n = 0; n < 4; ++n)
        Pf[n] = ld16(Ph + (16*n+lo)*128 + ((u32)(16*g + 64*kk2) ^ swr));
      #pragma unroll
      for (int md = 0; md < 2; ++md)
        #pragma unroll
        for (int n = 0; n < 4; ++n)
          y1a[hl][md][n] = mfma16(Vf[md], Pf[n], y1a[hl][md][n]);
    }
  } // heads

  __syncthreads();   // all waves done reading r1 (as Y)

  // ---- r1 += y1 (in place, wave-private column range) ----
  #pragma unroll
  for (int hl = 0; hl < 2; ++hl)
    #pragma unroll
    for (int md = 0; md < 2; ++md)
      #pragma unroll
      for (int n = 0; n < 4; ++n){
        int c0 = w*64 + hl*32 + 16*md + 4*g;
        char* p = r1 + (16*n+lo)*512 + ((u32)(c0*2) ^ swr);
        u32x2 old = *(const u32x2*)p;
        f32x4 a = y1a[hl][md][n];
        float o0 = bfl(old[0] & 0xffffu) + a[0];
        float o1 = bfl(old[0] >> 16)     + a[1];
        float o2 = bfl(old[1] & 0xffffu) + a[2];
        float o3 = bfl(old[1] >> 16)     + a[3];
        u32x2 nw; nw[0] = pk2(o0, o1); nw[1] = pk2(o2, o3);
        *(u32x2*)p = nw;
      }
  __syncthreads();

  // ---- proj: out = r1 @ proj_w^T + proj_b ----
  f32x4 ap[4][4] = {};
  #pragma unroll
  for (int kk = 0; kk < 8; ++kk){
    bf16x8 Af[4], Bp[4];
    #pragma unroll
    for (int m = 0; m < 4; ++m)
      Af[m] = ld16(r1 + (16*m+lo)*512 + ((u32)(kk*64 + 16*g) ^ swr));
    #pragma unroll
    for (int n = 0; n < 4; ++n){
      int off = (w*64 + 16*n + lo)*256 + kk*32 + 8*g;
      Bp[n] = loadw<BW>(wb + 196608 + off, pwf + off);
    }
    #pragma unroll
    for (int m = 0; m < 4; ++m)
      #pragma unroll
      for (int n = 0; n < 4; ++n)
        ap[m][n] = mfma16(Af[m], Bp[n], ap[m][n]);
  }
  float* ob = out + (size_t)b * 16384;
  #pragma unroll
  for (int m = 0; m < 4; ++m)
    #pragma unroll
    for (int n = 0; n < 4; ++n){
      int j = w*64 + 16*n + lo;
      float bias = pb[j];
      #pragma unroll
      for (int r = 0; r < 4; ++r)
        ob[(16*m + 4*g + r)*256 + j] = ap[m][n][r] + bias;
    }
}

extern "C" void kernel_launch(void* const* d_in, const int* in_sizes, int n_in,
                              void* d_out, int out_size, void* d_ws, size_t ws_size,
                              hipStream_t stream) {
  (void)n_in; (void)out_size;
  const float* x  = (const float*)d_in[0];
  const float* y  = (const float*)d_in[1];
  // d_in[2] (z) is unused by the reference forward
  const float* qw = (const float*)d_in[3];
  const float* qb = (const float*)d_in[4];
  const float* kw = (const float*)d_in[5];
  const float* kb = (const float*)d_in[6];
  const float* vw = (const float*)d_in[7];
  const float* vb = (const float*)d_in[8];
  const float* pw = (const float*)d_in[9];
  const float* pb = (const float*)d_in[10];
  float* out = (float*)d_out;
  const int Bn = in_sizes[0] / 16384;   // 2048

  const bool useWs = ws_size >= (size_t)524288;
  if (useWs){
    u16* wsb = (u16*)d_ws;
    prep_w<<<64, 256, 0, stream>>>(qw, kw, vw, pw, wsb);
    (void)hipFuncSetAttribute(reinterpret_cast<const void*>(&fused_ca<true>),
                              hipFuncAttributeMaxDynamicSharedMemorySize, 81920);
    fused_ca<true><<<Bn, 256, 81920, stream>>>(x, y, wsb, qw, kw, vw, pw,
                                               qb, kb, vb, pb, out);
  } else {
    (void)hipFuncSetAttribute(reinterpret_cast<const void*>(&fused_ca<false>),
                              hipFuncAttributeMaxDynamicSharedMemorySize, 81920);
    fused_ca<false><<<Bn, 256, 81920, stream>>>(x, y, (const u16*)d_ws, qw, kw, vw, pw,
                                                qb, kb, vb, pb, out);
  }
}

// Round 2
// 348.932 us; speedup vs baseline: 1.0854x; 1.0854x over previous
//
#include <hip/hip_runtime.h>

typedef __bf16 bf16x8 __attribute__((ext_vector_type(8)));
typedef float  f32x4  __attribute__((ext_vector_type(4)));
typedef unsigned int u32x4 __attribute__((ext_vector_type(4)));
typedef unsigned int u32x2 __attribute__((ext_vector_type(2)));
typedef unsigned int u32;
typedef unsigned short u16;

#define DEVI static __device__ __forceinline__

// Bn=2048, L=64, C=256, NH=8, HD=32
static constexpr float KSCALE = 0.17677669529663687f;  // 32^-0.5

DEVI u32 pk2(float a, float b){
  u16 ha = __builtin_bit_cast(u16, (__bf16)a);
  u16 hb = __builtin_bit_cast(u16, (__bf16)b);
  return (u32)ha | ((u32)hb << 16);
}
DEVI float bfl(u32 bits16){            // low 16 bits hold a bf16
  union { u32 i; float f; } v; v.i = bits16 << 16; return v.f;
}
DEVI bf16x8 ld16(const void* p){ return __builtin_bit_cast(bf16x8, *(const u32x4*)p); }
DEVI f32x4 mfma16(bf16x8 a, bf16x8 b, f32x4 c){
  return __builtin_amdgcn_mfma_f32_16x16x32_bf16(a, b, c, 0, 0, 0);
}

template<bool BW>
DEVI bf16x8 loadw(const u16* wbp, const float* wfp){
  if constexpr (BW){
    return ld16(wbp);
  } else {
    f32x4 a = *(const f32x4*)wfp;
    f32x4 b = *(const f32x4*)(wfp + 4);
    u32x4 pc; pc[0]=pk2(a[0],a[1]); pc[1]=pk2(a[2],a[3]); pc[2]=pk2(b[0],b[1]); pc[3]=pk2(b[2],b[3]);
    return __builtin_bit_cast(bf16x8, pc);
  }
}

// Permuted weight layout: frag block (M, R, kk) is 1KB contiguous, lane-major:
//   dst[(((M*16+R)*8+kk)*64 + l)*8 + e] = W_M[R*16 + (l&15)][kk*32 + (l>>4)*8 + e]
// so the in-kernel load  ld16(wb + frag*512 + l*8)  is a fully-coalesced 1KB stream.
__global__ void prep_w(const float* __restrict__ qw, const float* __restrict__ kw,
                       const float* __restrict__ vw, const float* __restrict__ pw,
                       u16* __restrict__ dst){
  int blk = blockIdx.x;            // 512 blocks: M(2b) R(4b) kk(3b)
  int l   = threadIdx.x;           // 64
  int M = blk >> 7, R = (blk >> 3) & 15, kk = blk & 7;
  const float* W = (M==0) ? qw : (M==1) ? kw : (M==2) ? vw : pw;
  const float* src = W + (R*16 + (l&15))*256 + kk*32 + (l>>4)*8;
  f32x4 a  = *(const f32x4*)src;
  f32x4 b2 = *(const f32x4*)(src + 4);
  u32x4 pc; pc[0]=pk2(a[0],a[1]); pc[1]=pk2(a[2],a[3]); pc[2]=pk2(b2[0],b2[1]); pc[3]=pk2(b2[2],b2[3]);
  *(u32x4*)(dst + (size_t)blk*512 + l*8) = pc;
}

DEVI const u16* wfrag(const u16* wb, int M, int R, int kk, int l){
  return wb + ((((M<<4) + R)<<3) + kk)*512 + l*8;
}

// One block per batch item. 256 threads = 4 waves; wave w owns heads {2w,2w+1}
// (channel cols [64w,64w+64)).  LDS 80KB: r1[64][256]bf16 (pitch 512B, XOR-swizzled)
// + per-wave {Qh[64][32], Kh[64][32] (pitch 64B), VT[32][64] (pitch 128B),
//   P[64][64] (pitch 128B) aliased over Qh+Kh}.  Epilogue reuses r1 as [32][256]f32.
template<bool BW>
__global__ __launch_bounds__(256, 2)
void fused_ca(const float* __restrict__ x, const float* __restrict__ y,
              const u16* __restrict__ wb,
              const float* __restrict__ qwf, const float* __restrict__ kwf,
              const float* __restrict__ vwf, const float* __restrict__ pwf,
              const float* __restrict__ qb, const float* __restrict__ kb,
              const float* __restrict__ vb, const float* __restrict__ pb,
              float* __restrict__ out)
{
  extern __shared__ char smem[];
  const int b  = blockIdx.x;
  const int t  = threadIdx.x;
  const int w  = t >> 6;
  const int l  = t & 63;
  const int lo = l & 15;
  const int g  = l >> 4;
  const u32 swr = (u32)(lo & 7) << 4;   // row-XOR swizzle, 128B/512B pitch buffers
  const u32 sw4 = (u32)(lo & 3) << 4;   // row-XOR swizzle, 64B pitch buffers

  char* r1 = smem;                      // Y then (y+y1), bf16; then f32 out-stage
  char* wbp = smem + 32768 + w*12288;
  char* Qh = wbp;                       // [i][d] head-slice, pitch 64B
  char* Kh = wbp + 4096;                // [k][d] head-slice, pitch 64B
  char* VT = wbp + 8192;                // [d][k] (V^T), pitch 128B
  char* Ph = wbp;                       // [q][k], pitch 128B, aliases Qh+Kh

  const float* yb = y + (size_t)b * 16384;
  const float* xb = x + (size_t)b * 16384;

  // ---- stage Y -> r1 (bf16, swizzled), coalesced 1KB/inst ----
  #pragma unroll
  for (int j = 0; j < 16; ++j){
    int idx = t + 256*j;
    int row = idx >> 6;
    int c0  = (idx & 63) * 4;
    f32x4 v = *(const f32x4*)(yb + row*256 + c0);
    u32x2 o; o[0] = pk2(v[0], v[1]); o[1] = pk2(v[2], v[3]);
    *(u32x2*)(r1 + row*512 + ((u32)(c0*2) ^ ((u32)(row&7) << 4))) = o;
  }
  __syncthreads();

  f32x4 y1a[2][2][4] = {};   // [head][d-frag][q-frag] : Y1^T[d][q] accumulators

  #pragma unroll
  for (int hl = 0; hl < 2; ++hl){
    const int cb = w*64 + hl*32;        // global channel base of this head
    const int Rb = w*4 + hl*2;          // weight rowblock base

    // ---- Q-GEMM (transposed: D[j][i] = sum_c qw[j][c] * Y[i][c]) ----
    f32x4 aq[2][4] = {};
    #pragma unroll
    for (int kk = 0; kk < 8; ++kk){
      bf16x8 A[2], Bf[4];
      #pragma unroll
      for (int m = 0; m < 2; ++m){
        int off = (cb + 16*m + lo)*256 + kk*32 + 8*g;
        A[m] = loadw<BW>(wfrag(wb, 0, Rb + m, kk, l), qwf + off);
      }
      #pragma unroll
      for (int n = 0; n < 4; ++n)
        Bf[n] = ld16(r1 + (16*n+lo)*512 + ((u32)(kk*64 + 16*g) ^ swr));
      #pragma unroll
      for (int m = 0; m < 2; ++m)
        #pragma unroll
        for (int n = 0; n < 4; ++n)
          aq[m][n] = mfma16(A[m], Bf[n], aq[m][n]);
    }
    #pragma unroll
    for (int m = 0; m < 2; ++m){
      f32x4 bias = *(const f32x4*)(qb + cb + 16*m + 4*g);
      #pragma unroll
      for (int n = 0; n < 4; ++n){
        float v0 = (aq[m][n][0] + bias[0]) * KSCALE;
        float v1 = (aq[m][n][1] + bias[1]) * KSCALE;
        float v2 = (aq[m][n][2] + bias[2]) * KSCALE;
        float v3 = (aq[m][n][3] + bias[3]) * KSCALE;
        u32x2 o; o[0] = pk2(v0, v1); o[1] = pk2(v2, v3);
        *(u32x2*)(Qh + (16*n+lo)*64 + ((u32)(32*m + 8*g) ^ sw4)) = o;
      }
    }

    // ---- fused K-GEMM (transposed) + V-GEMM (normal), sharing X fragments ----
    f32x4 ak[2][4] = {};   // [j-frag][i-frag]
    f32x4 av[4][2] = {};   // [i-frag][j-frag]
    #pragma unroll
    for (int kk = 0; kk < 8; ++kk){
      bf16x8 WA[2], WB2[2], XF[4];
      #pragma unroll
      for (int m = 0; m < 2; ++m){
        int off = (cb + 16*m + lo)*256 + kk*32 + 8*g;
        WA[m] = loadw<BW>(wfrag(wb, 1, Rb + m, kk, l), kwf + off);
      }
      #pragma unroll
      for (int n = 0; n < 2; ++n){
        int off = (cb + 16*n + lo)*256 + kk*32 + 8*g;
        WB2[n] = loadw<BW>(wfrag(wb, 2, Rb + n, kk, l), vwf + off);
      }
      #pragma unroll
      for (int f = 0; f < 4; ++f){
        const float* px = xb + (16*f + lo)*256 + kk*32 + 8*g;
        f32x4 u0 = *(const f32x4*)px;
        f32x4 u1 = *(const f32x4*)(px + 4);
        u32x4 pc; pc[0]=pk2(u0[0],u0[1]); pc[1]=pk2(u0[2],u0[3]);
                  pc[2]=pk2(u1[0],u1[1]); pc[3]=pk2(u1[2],u1[3]);
        XF[f] = __builtin_bit_cast(bf16x8, pc);
      }
      #pragma unroll
      for (int f = 0; f < 4; ++f){
        #pragma unroll
        for (int m = 0; m < 2; ++m)
          ak[m][f] = mfma16(WA[m], XF[f], ak[m][f]);
        #pragma unroll
        for (int n = 0; n < 2; ++n)
          av[f][n] = mfma16(XF[f], WB2[n], av[f][n]);
      }
    }
    #pragma unroll
    for (int m = 0; m < 2; ++m){
      f32x4 bias = *(const f32x4*)(kb + cb + 16*m + 4*g);
      #pragma unroll
      for (int f = 0; f < 4; ++f){
        u32x2 o; o[0] = pk2(ak[m][f][0]+bias[0], ak[m][f][1]+bias[1]);
                 o[1] = pk2(ak[m][f][2]+bias[2], ak[m][f][3]+bias[3]);
        *(u32x2*)(Kh + (16*f+lo)*64 + ((u32)(32*m + 8*g) ^ sw4)) = o;
      }
    }
    #pragma unroll
    for (int n = 0; n < 2; ++n){
      float bias = vb[cb + 16*n + lo];
      #pragma unroll
      for (int f = 0; f < 4; ++f){
        u32x2 o; o[0] = pk2(av[f][n][0]+bias, av[f][n][1]+bias);
                 o[1] = pk2(av[f][n][2]+bias, av[f][n][3]+bias);
        *(u32x2*)(VT + (16*n+lo)*128 + ((u32)(32*f + 8*g) ^ swr)) = o;
      }
    }

    // ---- S^T = K @ Q^T  (one K=32 MFMA per 16x16 fragment) ----
    bf16x8 Kf[4], Qf[4];
    #pragma unroll
    for (int m = 0; m < 4; ++m)
      Kf[m] = ld16(Kh + (16*m+lo)*64 + ((u32)(16*g) ^ sw4));
    #pragma unroll
    for (int n = 0; n < 4; ++n)
      Qf[n] = ld16(Qh + (16*n+lo)*64 + ((u32)(16*g) ^ sw4));
    f32x4 s[4][4];
    const f32x4 zero = {};
    #pragma unroll
    for (int m = 0; m < 4; ++m)
      #pragma unroll
      for (int n = 0; n < 4; ++n)
        s[m][n] = mfma16(Kf[m], Qf[n], zero);

    // ---- softmax_plus_one over k (rows of S^T): 16 local + 2 shfl ----
    #pragma unroll
    for (int n = 0; n < 4; ++n){
      float mx = s[0][n][0];
      #pragma unroll
      for (int m = 0; m < 4; ++m)
        #pragma unroll
        for (int r = 0; r < 4; ++r)
          mx = fmaxf(mx, s[m][n][r]);
      mx = fmaxf(mx, __shfl_xor(mx, 16));
      mx = fmaxf(mx, __shfl_xor(mx, 32));
      float sum = 0.f;
      #pragma unroll
      for (int m = 0; m < 4; ++m)
        #pragma unroll
        for (int r = 0; r < 4; ++r){
          float e = __expf(s[m][n][r] - mx);
          s[m][n][r] = e; sum += e;
        }
      sum += __shfl_xor(sum, 16);
      sum += __shfl_xor(sum, 32);
      float rin = 1.0f / (sum + 1.0f);
      #pragma unroll
      for (int m = 0; m < 4; ++m)
        #pragma unroll
        for (int r = 0; r < 4; ++r)
          s[m][n][r] *= rin;
    }

    // ---- write P[q][k] bf16 (Qh/Kh dead now; Ph aliases them) ----
    #pragma unroll
    for (int m = 0; m < 4; ++m)
      #pragma unroll
      for (int n = 0; n < 4; ++n){
        u32x2 o; o[0] = pk2(s[m][n][0], s[m][n][1]);
                 o[1] = pk2(s[m][n][2], s[m][n][3]);
        *(u32x2*)(Ph + (16*n+lo)*128 + ((u32)(32*m + 8*g) ^ swr)) = o;
      }

    // ---- PV: Y1^T = V^T @ P^T ----
    #pragma unroll
    for (int kk2 = 0; kk2 < 2; ++kk2){
      bf16x8 Vf[2], Pf[4];
      #pragma unroll
      for (int md = 0; md < 2; ++md)
        Vf[md] = ld16(VT + (16*md+lo)*128 + ((u32)(16*g + 64*kk2) ^ swr));
      #pragma unroll
      for (int n = 0; n < 4; ++n)
        Pf[n] = ld16(Ph + (16*n+lo)*128 + ((u32)(16*g + 64*kk2) ^ swr));
      #pragma unroll
      for (int md = 0; md < 2; ++md)
        #pragma unroll
        for (int n = 0; n < 4; ++n)
          y1a[hl][md][n] = mfma16(Vf[md], Pf[n], y1a[hl][md][n]);
    }
  } // heads

  __syncthreads();   // all waves done reading r1 (as Y)

  // ---- r1 += y1 (in place, wave-private column range) ----
  #pragma unroll
  for (int hl = 0; hl < 2; ++hl)
    #pragma unroll
    for (int md = 0; md < 2; ++md)
      #pragma unroll
      for (int n = 0; n < 4; ++n){
        int c0 = w*64 + hl*32 + 16*md + 4*g;
        char* p = r1 + (16*n+lo)*512 + ((u32)(c0*2) ^ swr);
        u32x2 old = *(const u32x2*)p;
        f32x4 a = y1a[hl][md][n];
        float o0 = bfl(old[0] & 0xffffu) + a[0];
        float o1 = bfl(old[0] >> 16)     + a[1];
        float o2 = bfl(old[1] & 0xffffu) + a[2];
        float o3 = bfl(old[1] >> 16)     + a[3];
        u32x2 nw; nw[0] = pk2(o0, o1); nw[1] = pk2(o2, o3);
        *(u32x2*)p = nw;
      }
  __syncthreads();

  // ---- proj: out = r1 @ proj_w^T + proj_b ----
  f32x4 ap[4][4] = {};
  #pragma unroll
  for (int kk = 0; kk < 8; ++kk){
    bf16x8 Af[4], Bp[4];
    #pragma unroll
    for (int m = 0; m < 4; ++m)
      Af[m] = ld16(r1 + (16*m+lo)*512 + ((u32)(kk*64 + 16*g) ^ swr));
    #pragma unroll
    for (int n = 0; n < 4; ++n){
      int off = (w*64 + 16*n + lo)*256 + kk*32 + 8*g;
      Bp[n] = loadw<BW>(wfrag(wb, 3, w*4 + n, kk, l), pwf + off);
    }
    #pragma unroll
    for (int m = 0; m < 4; ++m)
      #pragma unroll
      for (int n = 0; n < 4; ++n)
        ap[m][n] = mfma16(Af[m], Bp[n], ap[m][n]);
  }

  // ---- bias, then coalesced store via LDS transpose (r1 reused as [32][256] f32) ----
  float pbv[4];
  #pragma unroll
  for (int n = 0; n < 4; ++n) pbv[n] = pb[w*64 + 16*n + lo];
  #pragma unroll
  for (int m = 0; m < 4; ++m)
    #pragma unroll
    for (int n = 0; n < 4; ++n)
      #pragma unroll
      for (int r = 0; r < 4; ++r)
        ap[m][n][r] += pbv[n];

  float* ob = out + (size_t)b * 16384;
  #pragma unroll
  for (int half = 0; half < 2; ++half){
    __syncthreads();   // r1's previous contents fully consumed
    #pragma unroll
    for (int mm = 0; mm < 2; ++mm)
      #pragma unroll
      for (int n = 0; n < 4; ++n){
        int col = w*64 + 16*n + lo;
        #pragma unroll
        for (int r = 0; r < 4; ++r){
          int row = mm*16 + 4*g + r;                      // 0..31
          u32 byteoff = ((u32)(row*1024 + col*4)) ^ ((u32)(row & 4) << 4);
          *(float*)(r1 + byteoff) = ap[half*2 + mm][n][r];
        }
      }
    __syncthreads();
    #pragma unroll
    for (int i = 0; i < 8; ++i){
      int id  = i*256 + t;
      int row = id >> 6;                                  // 0..31
      int cc  = id & 63;
      u32 byteoff = (u32)(row*1024) + ((u32)(cc ^ (row & 4)) << 4);
      f32x4 v = *(const f32x4*)(r1 + byteoff);
      *(f32x4*)(ob + (half*32 + row)*256 + cc*4) = v;
    }
  }
}

extern "C" void kernel_launch(void* const* d_in, const int* in_sizes, int n_in,
                              void* d_out, int out_size, void* d_ws, size_t ws_size,
                              hipStream_t stream) {
  (void)n_in; (void)out_size;
  const float* x  = (const float*)d_in[0];
  const float* y  = (const float*)d_in[1];
  // d_in[2] (z) is unused by the reference forward
  const float* qw = (const float*)d_in[3];
  const float* qb = (const float*)d_in[4];
  const float* kw = (const float*)d_in[5];
  const float* kb = (const float*)d_in[6];
  const float* vw = (const float*)d_in[7];
  const float* vb = (const float*)d_in[8];
  const float* pw = (const float*)d_in[9];
  const float* pb = (const float*)d_in[10];
  float* out = (float*)d_out;
  const int Bn = in_sizes[0] / 16384;   // 2048

  const bool useWs = ws_size >= (size_t)524288;
  if (useWs){
    u16* wsb = (u16*)d_ws;
    prep_w<<<512, 64, 0, stream>>>(qw, kw, vw, pw, wsb);
    (void)hipFuncSetAttribute(reinterpret_cast<const void*>(&fused_ca<true>),
                              hipFuncAttributeMaxDynamicSharedMemorySize, 81920);
    fused_ca<true><<<Bn, 256, 81920, stream>>>(x, y, wsb, qw, kw, vw, pw,
                                               qb, kb, vb, pb, out);
  } else {
    (void)hipFuncSetAttribute(reinterpret_cast<const void*>(&fused_ca<false>),
                              hipFuncAttributeMaxDynamicSharedMemorySize, 81920);
    fused_ca<false><<<Bn, 256, 81920, stream>>>(x, y, (const u16*)d_ws, qw, kw, vw, pw,
                                                qb, kb, vb, pb, out);
  }
}

// Round 3
// 173.017 us; speedup vs baseline: 2.1890x; 2.0168x over previous
//
#include <hip/hip_runtime.h>

typedef __bf16 bf16x8 __attribute__((ext_vector_type(8)));
typedef __bf16 bf16x4 __attribute__((ext_vector_type(4)));
typedef short  s16x4  __attribute__((ext_vector_type(4)));
typedef float  f32x4  __attribute__((ext_vector_type(4)));
typedef unsigned int u32x4 __attribute__((ext_vector_type(4)));
typedef unsigned int u32x2 __attribute__((ext_vector_type(2)));
typedef unsigned int u32;
typedef unsigned short u16;

#define DEVI static __device__ __forceinline__

// Bn=2048, L=64, C=256, NH=8, HD=32
static constexpr float KSCALE = 0.17677669529663687f;  // 32^-0.5

DEVI u32 pk2(float a, float b){
  u16 ha = __builtin_bit_cast(u16, (__bf16)a);
  u16 hb = __builtin_bit_cast(u16, (__bf16)b);
  return (u32)ha | ((u32)hb << 16);
}
DEVI float bfl(u32 bits16){            // low 16 bits hold a bf16
  union { u32 i; float f; } v; v.i = bits16 << 16; return v.f;
}
DEVI u32x2 pkfrag(f32x4 v){ u32x2 o; o[0]=pk2(v[0],v[1]); o[1]=pk2(v[2],v[3]); return o; }
DEVI bf16x8 ld16(const void* p){ return __builtin_bit_cast(bf16x8, *(const u32x4*)p); }
DEVI f32x4 mfma16(bf16x8 a, bf16x8 b, f32x4 c){
  return __builtin_amdgcn_mfma_f32_16x16x32_bf16(a, b, c, 0, 0, 0);
}
// 16x16x16 bf16 MFMA: A/B frag layout A[row=lane&15][k=(lane>>4)*4+e] is the
// transpose of the C/D layout -> lets S and PV consume Q/K/V/P straight from
// accumulator registers (in-lane pack only, no LDS round-trip).
DEVI f32x4 mfma1616(u32x2 a, u32x2 b, f32x4 c){
#if __has_builtin(__builtin_amdgcn_mfma_f32_16x16x16_bf16)
  return __builtin_amdgcn_mfma_f32_16x16x16_bf16(
      __builtin_bit_cast(bf16x4, a), __builtin_bit_cast(bf16x4, b), c, 0, 0, 0);
#elif __has_builtin(__builtin_amdgcn_mfma_f32_16x16x16bf16_1k)
  return __builtin_amdgcn_mfma_f32_16x16x16bf16_1k(
      __builtin_bit_cast(s16x4, a), __builtin_bit_cast(s16x4, b), c, 0, 0, 0);
#else
  asm("v_mfma_f32_16x16x16_bf16 %0, %1, %2, %0" : "+v"(c) : "v"(a), "v"(b));
  return c;
#endif
}

template<bool BW>
DEVI bf16x8 loadw(const u16* wbp, const float* wfp){
  if constexpr (BW){
    return ld16(wbp);
  } else {
    f32x4 a = *(const f32x4*)wfp;
    f32x4 b = *(const f32x4*)(wfp + 4);
    u32x4 pc; pc[0]=pk2(a[0],a[1]); pc[1]=pk2(a[2],a[3]); pc[2]=pk2(b[0],b[1]); pc[3]=pk2(b[2],b[3]);
    return __builtin_bit_cast(bf16x8, pc);
  }
}

// Permuted weight layout: frag block (M, R, kk) is 1KB contiguous, lane-major:
//   dst[(((M*16+R)*8+kk)*64 + l)*8 + e] = W_M[R*16 + (l&15)][kk*32 + (l>>4)*8 + e]
__global__ void prep_w(const float* __restrict__ qw, const float* __restrict__ kw,
                       const float* __restrict__ vw, const float* __restrict__ pw,
                       u16* __restrict__ dst){
  int blk = blockIdx.x;            // 512 blocks: M(2b) R(4b) kk(3b)
  int l   = threadIdx.x;           // 64
  int M = blk >> 7, R = (blk >> 3) & 15, kk = blk & 7;
  const float* W = (M==0) ? qw : (M==1) ? kw : (M==2) ? vw : pw;
  const float* src = W + (R*16 + (l&15))*256 + kk*32 + (l>>4)*8;
  f32x4 a  = *(const f32x4*)src;
  f32x4 b2 = *(const f32x4*)(src + 4);
  u32x4 pc; pc[0]=pk2(a[0],a[1]); pc[1]=pk2(a[2],a[3]); pc[2]=pk2(b2[0],b2[1]); pc[3]=pk2(b2[2],b2[3]);
  *(u32x4*)(dst + (size_t)blk*512 + l*8) = pc;
}

DEVI const u16* wfrag(const u16* wb, int M, int R, int kk, int l){
  return wb + ((((M<<4) + R)<<3) + kk)*512 + l*8;
}

// One block per batch item. 256 threads = 4 waves; wave w owns heads {2w,2w+1}.
// LDS 64KB: r1 = Y/(y+y1) bf16 [64][256] pitch 512B swizzled, Xs = X bf16 same.
// Attention intermediates (Q,K,V,P) never touch LDS (16x16x16 MFMA trick).
template<bool BW>
__global__ __launch_bounds__(256, 2)
void fused_ca(const float* __restrict__ x, const float* __restrict__ y,
              const u16* __restrict__ wb,
              const float* __restrict__ qwf, const float* __restrict__ kwf,
              const float* __restrict__ vwf, const float* __restrict__ pwf,
              const float* __restrict__ qb, const float* __restrict__ kb,
              const float* __restrict__ vb, const float* __restrict__ pb,
              float* __restrict__ out)
{
  extern __shared__ char smem[];
  const int b  = blockIdx.x;
  const int t  = threadIdx.x;
  const int w  = t >> 6;
  const int l  = t & 63;
  const int lo = l & 15;
  const int g  = l >> 4;
  const u32 swr = (u32)(lo & 7) << 4;

  char* r1 = smem;                      // 32KB
  char* Xs = smem + 32768;              // 32KB

  const float* yb = y + (size_t)b * 16384;
  const float* xb = x + (size_t)b * 16384;

  // ---- stage Y -> r1 (bf16, swizzled) ----
  #pragma unroll
  for (int j = 0; j < 16; ++j){
    int idx = t + 256*j;
    int row = idx >> 6;
    int c0  = (idx & 63) * 4;
    f32x4 v = *(const f32x4*)(yb + row*256 + c0);
    u32x2 o; o[0] = pk2(v[0], v[1]); o[1] = pk2(v[2], v[3]);
    *(u32x2*)(r1 + row*512 + ((u32)(c0*2) ^ ((u32)(row&7) << 4))) = o;
  }
  // issue X batch 0 (rows 0..31) while Y settles
  f32x4 xr[8];
  #pragma unroll
  for (int j = 0; j < 8; ++j){
    int idx = t + 256*j;
    xr[j] = *(const f32x4*)(xb + (idx>>6)*256 + (idx & 63)*4);
  }
  __syncthreads();   // Y readable

  // ---- Q-GEMMs (both heads), X staging interleaved ----
  u32x2 aqpk[2][8];    // [hl][m*4+n]
  #pragma unroll
  for (int hl = 0; hl < 2; ++hl){
    const int cb = w*64 + hl*32;
    const int Rb = w*4 + hl*2;
    f32x4 aq[2][4] = {};
    #pragma unroll
    for (int kk = 0; kk < 8; ++kk){
      bf16x8 A[2], Bf[4];
      #pragma unroll
      for (int m = 0; m < 2; ++m){
        int off = (cb + 16*m + lo)*256 + kk*32 + 8*g;
        A[m] = loadw<BW>(wfrag(wb, 0, Rb + m, kk, l), qwf + off);
      }
      #pragma unroll
      for (int n = 0; n < 4; ++n)
        Bf[n] = ld16(r1 + (16*n+lo)*512 + ((u32)(kk*64 + 16*g) ^ swr));
      #pragma unroll
      for (int m = 0; m < 2; ++m)
        #pragma unroll
        for (int n = 0; n < 4; ++n)
          aq[m][n] = mfma16(A[m], Bf[n], aq[m][n]);
    }
    #pragma unroll
    for (int m = 0; m < 2; ++m){
      f32x4 bias = *(const f32x4*)(qb + cb + 16*m + 4*g);
      #pragma unroll
      for (int n = 0; n < 4; ++n){
        f32x4 v; 
        #pragma unroll
        for (int r = 0; r < 4; ++r) v[r] = (aq[m][n][r] + bias[r]) * KSCALE;
        aqpk[hl][m*4+n] = pkfrag(v);
      }
    }
    if (hl == 0){
      // write X batch 0, issue X batch 1
      #pragma unroll
      for (int j = 0; j < 8; ++j){
        int idx = t + 256*j;
        int row = idx >> 6;
        int c0  = (idx & 63) * 4;
        u32x2 o; o[0] = pk2(xr[j][0], xr[j][1]); o[1] = pk2(xr[j][2], xr[j][3]);
        *(u32x2*)(Xs + row*512 + ((u32)(c0*2) ^ ((u32)(row&7) << 4))) = o;
      }
      #pragma unroll
      for (int j = 0; j < 8; ++j){
        int idx = t + 256*(j+8);
        xr[j] = *(const f32x4*)(xb + (idx>>6)*256 + (idx & 63)*4);
      }
    }
  }
  #pragma unroll
  for (int j = 0; j < 8; ++j){
    int idx = t + 256*(j+8);
    int row = idx >> 6;
    int c0  = (idx & 63) * 4;
    u32x2 o; o[0] = pk2(xr[j][0], xr[j][1]); o[1] = pk2(xr[j][2], xr[j][3]);
    *(u32x2*)(Xs + row*512 + ((u32)(c0*2) ^ ((u32)(row&7) << 4))) = o;
  }
  __syncthreads();   // X readable; all Q-GEMM r1 reads done

  // ---- per head: K/V GEMM -> attention -> residual ----
  #pragma unroll
  for (int hl = 0; hl < 2; ++hl){
    const int cb = w*64 + hl*32;
    const int Rb = w*4 + hl*2;

    f32x4 ak[2][4] = {};   // K^T tiles [m][f]
    f32x4 av[4][2] = {};   // V tiles [f][n]
    #pragma unroll
    for (int kk = 0; kk < 8; ++kk){
      bf16x8 WA[2], WB2[2], XF[4];
      #pragma unroll
      for (int m = 0; m < 2; ++m){
        int off = (cb + 16*m + lo)*256 + kk*32 + 8*g;
        WA[m] = loadw<BW>(wfrag(wb, 1, Rb + m, kk, l), kwf + off);
      }
      #pragma unroll
      for (int n = 0; n < 2; ++n){
        int off = (cb + 16*n + lo)*256 + kk*32 + 8*g;
        WB2[n] = loadw<BW>(wfrag(wb, 2, Rb + n, kk, l), vwf + off);
      }
      #pragma unroll
      for (int f = 0; f < 4; ++f)
        XF[f] = ld16(Xs + (16*f+lo)*512 + ((u32)(kk*64 + 16*g) ^ swr));
      #pragma unroll
      for (int f = 0; f < 4; ++f){
        #pragma unroll
        for (int m = 0; m < 2; ++m)
          ak[m][f] = mfma16(WA[m], XF[f], ak[m][f]);
        #pragma unroll
        for (int n = 0; n < 2; ++n)
          av[f][n] = mfma16(XF[f], WB2[n], av[f][n]);
      }
    }
    // pack K, V into A/B fragments (in-lane only)
    u32x2 akpk[8], avpk[8];   // [m*4+f], [f*2+n]
    #pragma unroll
    for (int m = 0; m < 2; ++m){
      f32x4 bias = *(const f32x4*)(kb + cb + 16*m + 4*g);
      #pragma unroll
      for (int f = 0; f < 4; ++f){
        f32x4 v;
        #pragma unroll
        for (int r = 0; r < 4; ++r) v[r] = ak[m][f][r] + bias[r];
        akpk[m*4+f] = pkfrag(v);
      }
    }
    #pragma unroll
    for (int n = 0; n < 2; ++n){
      float bias = vb[cb + 16*n + lo];
      #pragma unroll
      for (int f = 0; f < 4; ++f){
        f32x4 v;
        #pragma unroll
        for (int r = 0; r < 4; ++r) v[r] = av[f][n][r] + bias;
        avpk[f*2+n] = pkfrag(v);
      }
    }

    // ---- attention: per q-tile n, S (16x16x16) -> softmax+1 -> PV ----
    f32x4 y1h[2][4] = {};   // [md][n] : Y1^T tiles
    #pragma unroll
    for (int n = 0; n < 4; ++n){
      f32x4 s4[4];
      #pragma unroll
      for (int f = 0; f < 4; ++f){
        f32x4 acc = {};
        acc = mfma1616(akpk[0*4+f], aqpk[hl][0*4+n], acc);
        acc = mfma1616(akpk[1*4+f], aqpk[hl][1*4+n], acc);
        s4[f] = acc;
      }
      float mx = s4[0][0];
      #pragma unroll
      for (int f = 0; f < 4; ++f)
        #pragma unroll
        for (int r = 0; r < 4; ++r)
          mx = fmaxf(mx, s4[f][r]);
      mx = fmaxf(mx, __shfl_xor(mx, 16));
      mx = fmaxf(mx, __shfl_xor(mx, 32));
      float sum = 0.f;
      #pragma unroll
      for (int f = 0; f < 4; ++f)
        #pragma unroll
        for (int r = 0; r < 4; ++r){
          float e = __expf(s4[f][r] - mx);
          s4[f][r] = e; sum += e;
        }
      sum += __shfl_xor(sum, 16);
      sum += __shfl_xor(sum, 32);
      float rin = 1.0f / (sum + 1.0f);
      u32x2 spk[4];
      #pragma unroll
      for (int f = 0; f < 4; ++f){
        f32x4 v;
        #pragma unroll
        for (int r = 0; r < 4; ++r) v[r] = s4[f][r] * rin;
        spk[f] = pkfrag(v);
      }
      #pragma unroll
      for (int md = 0; md < 2; ++md)
        #pragma unroll
        for (int f = 0; f < 4; ++f)
          y1h[md][n] = mfma1616(avpk[f*2+md], spk[f], y1h[md][n]);
    }

    // ---- residual: r1 += y1 (wave-private cols; safe after bar2) ----
    #pragma unroll
    for (int md = 0; md < 2; ++md)
      #pragma unroll
      for (int n = 0; n < 4; ++n){
        int c0 = cb + 16*md + 4*g;
        char* p = r1 + (16*n+lo)*512 + ((u32)(c0*2) ^ swr);
        u32x2 old = *(const u32x2*)p;
        f32x4 a = y1h[md][n];
        float o0 = bfl(old[0] & 0xffffu) + a[0];
        float o1 = bfl(old[0] >> 16)     + a[1];
        float o2 = bfl(old[1] & 0xffffu) + a[2];
        float o3 = bfl(old[1] >> 16)     + a[3];
        u32x2 nw; nw[0] = pk2(o0, o1); nw[1] = pk2(o2, o3);
        *(u32x2*)p = nw;
      }
  } // heads

  __syncthreads();

  // ---- proj: out = r1 @ proj_w^T + proj_b ----
  f32x4 ap[4][4] = {};
  #pragma unroll
  for (int kk = 0; kk < 8; ++kk){
    bf16x8 Af[4], Bp[4];
    #pragma unroll
    for (int m = 0; m < 4; ++m)
      Af[m] = ld16(r1 + (16*m+lo)*512 + ((u32)(kk*64 + 16*g) ^ swr));
    #pragma unroll
    for (int n = 0; n < 4; ++n){
      int off = (w*64 + 16*n + lo)*256 + kk*32 + 8*g;
      Bp[n] = loadw<BW>(wfrag(wb, 3, w*4 + n, kk, l), pwf + off);
    }
    #pragma unroll
    for (int m = 0; m < 4; ++m)
      #pragma unroll
      for (int n = 0; n < 4; ++n)
        ap[m][n] = mfma16(Af[m], Bp[n], ap[m][n]);
  }

  float pbv[4];
  #pragma unroll
  for (int n = 0; n < 4; ++n) pbv[n] = pb[w*64 + 16*n + lo];
  #pragma unroll
  for (int m = 0; m < 4; ++m)
    #pragma unroll
    for (int n = 0; n < 4; ++n)
      #pragma unroll
      for (int r = 0; r < 4; ++r)
        ap[m][n][r] += pbv[n];

  // ---- coalesced store via LDS transpose (r1 reused as [32][256] f32) ----
  float* ob = out + (size_t)b * 16384;
  #pragma unroll
  for (int half = 0; half < 2; ++half){
    __syncthreads();
    #pragma unroll
    for (int mm = 0; mm < 2; ++mm)
      #pragma unroll
      for (int n = 0; n < 4; ++n){
        int col = w*64 + 16*n + lo;
        #pragma unroll
        for (int r = 0; r < 4; ++r){
          int row = mm*16 + 4*g + r;                      // 0..31
          u32 byteoff = ((u32)(row*1024 + col*4)) ^ ((u32)(row & 4) << 4);
          *(float*)(r1 + byteoff) = ap[half*2 + mm][n][r];
        }
      }
    __syncthreads();
    #pragma unroll
    for (int i = 0; i < 8; ++i){
      int id  = i*256 + t;
      int row = id >> 6;                                  // 0..31
      int cc  = id & 63;
      u32 byteoff = (u32)(row*1024) + ((u32)(cc ^ (row & 4)) << 4);
      f32x4 v = *(const f32x4*)(r1 + byteoff);
      *(f32x4*)(ob + (half*32 + row)*256 + cc*4) = v;
    }
  }
}

extern "C" void kernel_launch(void* const* d_in, const int* in_sizes, int n_in,
                              void* d_out, int out_size, void* d_ws, size_t ws_size,
                              hipStream_t stream) {
  (void)n_in; (void)out_size;
  const float* x  = (const float*)d_in[0];
  const float* y  = (const float*)d_in[1];
  // d_in[2] (z) is unused by the reference forward
  const float* qw = (const float*)d_in[3];
  const float* qb = (const float*)d_in[4];
  const float* kw = (const float*)d_in[5];
  const float* kb = (const float*)d_in[6];
  const float* vw = (const float*)d_in[7];
  const float* vb = (const float*)d_in[8];
  const float* pw = (const float*)d_in[9];
  const float* pb = (const float*)d_in[10];
  float* out = (float*)d_out;
  const int Bn = in_sizes[0] / 16384;   // 2048

  const bool useWs = ws_size >= (size_t)524288;
  if (useWs){
    u16* wsb = (u16*)d_ws;
    prep_w<<<512, 64, 0, stream>>>(qw, kw, vw, pw, wsb);
    (void)hipFuncSetAttribute(reinterpret_cast<const void*>(&fused_ca<true>),
                              hipFuncAttributeMaxDynamicSharedMemorySize, 65536);
    fused_ca<true><<<Bn, 256, 65536, stream>>>(x, y, wsb, qw, kw, vw, pw,
                                               qb, kb, vb, pb, out);
  } else {
    (void)hipFuncSetAttribute(reinterpret_cast<const void*>(&fused_ca<false>),
                              hipFuncAttributeMaxDynamicSharedMemorySize, 65536);
    fused_ca<false><<<Bn, 256, 65536, stream>>>(x, y, (const u16*)d_ws, qw, kw, vw, pw,
                                                qb, kb, vb, pb, out);
  }
}